// Round 5
// baseline (323.362 us; speedup 1.0000x reference)
//
#include <hip/hip_runtime.h>
#include <hip/hip_bf16.h>

#define HH 128
#define WW 128
#define BB 4
#define NPIX 16384            // HH*WW
#define EPSV 1e-5f

using bfrag = __attribute__((ext_vector_type(8))) short;     // 8 bf16 (4 VGPRs)
using f32x4 = __attribute__((ext_vector_type(4))) float;
using us8   = __attribute__((ext_vector_type(8))) unsigned short;

__device__ __forceinline__ float bf2f(ushort u) {
  union { unsigned int i; float f; } x; x.i = ((unsigned int)u) << 16; return x.f;
}
__device__ __forceinline__ ushort f2bf(float f) {
  union { float f; unsigned int i; } x; x.f = f;
  unsigned int r = x.i + 0x7fffu + ((x.i >> 16) & 1u);   // RNE
  return (ushort)(r >> 16);
}

#define GLOAD16(gsrc, ldst) \
  __builtin_amdgcn_global_load_lds( \
      (const __attribute__((address_space(1))) unsigned int*)(gsrc), \
      (__attribute__((address_space(3))) unsigned int*)(ldst), 16, 0, 0)

// ---------------------------------------------------------------------------
// Implicit-GEMM conv via MFMA.  Tri-buffered LDS, counted vmcnt(6), ONE
// barrier per K-tile (T3+T4): loads for tile t+2 issue while computing t;
// vmcnt never drains inside the loop.
// Tile: BM=256 outs x BN=128 px (one image row), 8 waves, wave = 64x64.
// Buffer layout (48KB): A [256 outs][64 k] swizzled | B [128 px][64 k] swz.
// A pre-repacked in global to the exact LDS image -> linear global_load_lds;
// B staged with inverse-swizzled per-lane source (zero page at dx edges).
// Optional second GEMM phase (CIN2/TAPS2) accumulates into the same tile
// (fuses the 1x1 skip conv).  EPI: 0 = relu->bf16 NCHW, 3 = relu->fp32 NCHW,
// 4 = dual-bias, relu, LDS-transposed store -> bf16 [b][p][256].
// ---------------------------------------------------------------------------
template<int CIN1, int TAPS1, int CIN2, int TAPS2, int EPI>
__global__ __launch_bounds__(512, 1)
void convgemm(const ushort* __restrict__ B1,    // [b][16384][CIN1] bf16
              const ushort* __restrict__ B2,    // [b][16384][CIN2] bf16 (opt)
              const ushort* __restrict__ wR,    // repacked weights (tiles)
              const float*  __restrict__ tb,    // bias per out-channel
              const float*  __restrict__ tb2,   // second bias (EPI 4)
              void*          __restrict__ outp,
              const ushort* __restrict__ zerop) // 256B of zeros
{
  __shared__ char ldsb[3 * 49152];              // 3 x (A 32KB | B 16KB)
  constexpr int COUT = 256;
  constexpr int nch1 = CIN1 / 64;
  constexpr int nch2 = (CIN2 > 0) ? CIN2 / 64 : 0;
  constexpr int NCH  = TAPS1 * nch1 + TAPS2 * nch2;

  // XCD-bijective swizzle (512 blocks = 8 XCDs x 64): contiguous h per XCD
  const int nid = (blockIdx.x & 7) * 64 + (blockIdx.x >> 3);
  const int h = nid & 127;
  const int b = nid >> 7;
  const int tid  = threadIdx.x;
  const int lane = tid & 63;
  const int wid  = tid >> 6;
  const int m0 = (wid >> 1) * 64;               // 4 M-waves
  const int n0 = (wid & 1) * 64;                // 2 N-waves

  f32x4 acc[4][4];
  #pragma unroll
  for (int i = 0; i < 4; ++i)
    #pragma unroll
    for (int j = 0; j < 4; ++j) acc[i][j] = (f32x4){0.f, 0.f, 0.f, 0.f};

  // B staging lane constants: 2 segments of 8KB, row = pixel (w), slot = k/8
  int rowB[2], ro1[2], ro2[2];
  #pragma unroll
  for (int s = 0; s < 2; ++s) {
    const int boff = s * 8192 + tid * 16;
    rowB[s] = boff >> 7;                         // 0..127
    const int sl8 = ((((boff >> 4) & 7) ^ (rowB[s] & 7)) << 3);
    ro1[s] = rowB[s] * CIN1 + sl8;
    ro2[s] = (CIN2 > 0) ? rowB[s] * CIN2 + sl8 : 0;
  }
  const size_t B1base = (size_t)b * NPIX * CIN1;
  const size_t B2base = (CIN2 > 0) ? (size_t)b * NPIX * CIN2 : 0;

  auto stage = [&](int t, int buf) {
    char* base = ldsb + buf * 49152;
    const ushort* wsrc = wR + (size_t)t * (COUT * 64);
    #pragma unroll
    for (int s = 0; s < 4; ++s)                  // A: 4 loads (32KB, linear)
      GLOAD16((const char*)wsrc + s * 8192 + tid * 16,
              base + s * 8192 + tid * 16);
    const ushort* bch; int zr; bool oob, ph2;
    if (CIN2 == 0 || t < TAPS1 * nch1) {
      const int tap = t / nch1, ch = t - tap * nch1;     // nch1 pow2 -> shift
      const int dy = (TAPS1 == 9) ? tap / 3 - 1 : 0;
      const int dx = (TAPS1 == 9) ? tap - (tap / 3) * 3 - 1 : 0;
      const int hy = h + dy;
      oob = (hy < 0) | (hy >= HH);
      zr  = (dx < 0) ? 0 : ((dx > 0) ? 127 : -1);
      bch = B1 + B1base + (size_t)(hy * WW + dx) * CIN1 + ch * 64;
      ph2 = false;
    } else {
      const int ch = t - TAPS1 * nch1;
      oob = false; zr = -1;
      bch = B2 + B2base + (size_t)(h * WW) * CIN2 + ch * 64;
      ph2 = true;
    }
    #pragma unroll
    for (int s = 0; s < 2; ++s) {                // B: 2 loads (16KB)
      const int roff = ph2 ? ro2[s] : ro1[s];
      const ushort* bs = (oob || rowB[s] == zr) ? zerop : (bch + roff);
      GLOAD16(bs, base + 32768 + s * 8192 + tid * 16);
    }
  };

  auto compute = [&](int buf) {
    const char* base = ldsb + buf * 49152;
    __builtin_amdgcn_s_setprio(1);
    #pragma unroll
    for (int kc = 0; kc < 2; ++kc) {
      const int sw = ((((kc << 2) | (lane >> 4)) ^ (lane & 7)) << 4); // bytes
      bfrag af[4], bfv[4];
      #pragma unroll
      for (int mf = 0; mf < 4; ++mf)
        af[mf] = *(const bfrag*)(base + (m0 + mf * 16 + (lane & 15)) * 128 + sw);
      #pragma unroll
      for (int nf = 0; nf < 4; ++nf)
        bfv[nf] = *(const bfrag*)(base + 32768 + (n0 + nf * 16 + (lane & 15)) * 128 + sw);
      #pragma unroll
      for (int mf = 0; mf < 4; ++mf)
        #pragma unroll
        for (int nf = 0; nf < 4; ++nf)
          acc[mf][nf] = __builtin_amdgcn_mfma_f32_16x16x32_bf16(
              af[mf], bfv[nf], acc[mf][nf], 0, 0, 0);
    }
    __builtin_amdgcn_s_setprio(0);
  };

  // prologue: tiles 0 and 1 in flight (12 loads/wave)
  stage(0, 0);
  stage(1, 1);
  int cur = 0, nxt = 2;
  for (int t = 0; t < NCH - 1; ++t) {
    asm volatile("s_waitcnt vmcnt(6)" ::: "memory");   // tile t retired
    __builtin_amdgcn_s_barrier();                       // block: t's LDS valid
    __builtin_amdgcn_sched_barrier(0);                  // no hoist above
    if (t + 2 < NCH) stage(t + 2, nxt);                 // +6 loads in flight
    compute(cur);
    cur = (cur == 2) ? 0 : cur + 1;
    nxt = (nxt == 2) ? 0 : nxt + 1;
  }
  asm volatile("s_waitcnt vmcnt(0)" ::: "memory");      // last tile
  __builtin_amdgcn_s_barrier();
  __builtin_amdgcn_sched_barrier(0);
  compute(cur);

  if (EPI == 4) {
    // dual bias + relu, transpose via LDS, store bf16 [b][p][256] rows
    __syncthreads();                                    // all compute done
    ushort* ct = (ushort*)ldsb;                         // [128 px][264]
    const int pl0 = n0 + (lane & 15);
    #pragma unroll
    for (int mf = 0; mf < 4; ++mf) {
      #pragma unroll
      for (int r = 0; r < 4; ++r) {
        const int o = m0 + mf * 16 + (lane >> 4) * 4 + r;
        const float bias = tb[o] + tb2[o];
        #pragma unroll
        for (int nf = 0; nf < 4; ++nf)
          ct[(pl0 + nf * 16) * 264 + o] =
              f2bf(fmaxf(acc[mf][nf][r] + bias, 0.f));
      }
    }
    __syncthreads();
    const int p = tid >> 2;
    const int q = tid & 3;
    ushort* dst = (ushort*)outp +
                  ((size_t)b * NPIX + h * WW + p) * 256 + q * 64;
    const ushort* src = ct + p * 264 + q * 64;
    #pragma unroll
    for (int j = 0; j < 8; ++j)
      *(us8*)(dst + j * 8) = *(const us8*)(src + j * 8);
    return;
  }

  // EPI 0 / 3: C row = o (coalesced over p within 16-lane groups)
  const int pc0 = h * WW + n0 + (lane & 15);
  #pragma unroll
  for (int mf = 0; mf < 4; ++mf) {
    #pragma unroll
    for (int r = 0; r < 4; ++r) {
      const int o = m0 + mf * 16 + (lane >> 4) * 4 + r;
      const float bias = tb[o];
      #pragma unroll
      for (int nf = 0; nf < 4; ++nf) {
        const int p = pc0 + nf * 16;
        float v = fmaxf(acc[mf][nf][r] + bias, 0.f);
        const size_t oi = ((size_t)(b * 256 + o)) * NPIX + p;
        if (EPI == 0) ((ushort*)outp)[oi] = f2bf(v);
        else          ((float*)outp)[oi] = v;
      }
    }
  }
}

// ---------------------------------------------------------------------------
// fused weight repack: fold BN scale, bf16, swizzled LDS-image layout; emit tb.
// W is OIHW flat [COUT_local][CIN][TAPS]; tiles laid out cb + tap*nch + ch.
// ---------------------------------------------------------------------------
struct WSeg {
  const float *W, *g, *bb, *mm, *vv;
  ushort* dst; float* tb;
  int CIN, COUT, TAPS, o_off, cb, start, end;
};

__device__ __forceinline__ void wrepack_one(const WSeg& s, int e) {
  const int tap = e % s.TAPS;
  const int ci  = (e / s.TAPS) % s.CIN;
  const int o   = e / (s.TAPS * s.CIN);
  const int oi  = o + s.o_off;
  const float sc = s.g[o] * rsqrtf(s.vv[o] + EPSV);
  const int nch = s.CIN / 64;
  const int ch = ci >> 6, kl = ci & 63;
  const int slot = (kl >> 3) ^ (oi & 7);
  s.dst[(((size_t)((s.cb + tap * nch + ch) * s.COUT) + oi) << 6) +
        (slot << 3) + (kl & 7)] = f2bf(s.W[e] * sc);
  if (ci == 0 && tap == 0) s.tb[oi] = s.bb[o] - s.mm[o] * sc;
}

__global__ __launch_bounds__(256)
void wrepack_all(WSeg s0, WSeg s1, WSeg s2, WSeg s3, WSeg s4) {
  const int id = blockIdx.x * 256 + threadIdx.x;
  if (id < s0.end)      wrepack_one(s0, id - s0.start);
  else if (id < s1.end) wrepack_one(s1, id - s1.start);
  else if (id < s2.end) wrepack_one(s2, id - s2.start);
  else if (id < s3.end) wrepack_one(s3, id - s3.start);
  else if (id < s4.end) wrepack_one(s4, id - s4.start);
}

// ---------------------------------------------------------------------------
// x (fp32 NCHW) -> xT (bf16 [b][p][256]).  Thread = 4 px x 64 ch.
// ---------------------------------------------------------------------------
__global__ __launch_bounds__(256)
void repack_x(const float* __restrict__ x, ushort* __restrict__ xT)
{
  const int b  = blockIdx.z;
  const int cq = threadIdx.x >> 6;            // channel quarter
  const int pg = threadIdx.x & 63;
  const int p0 = blockIdx.x * 256 + pg * 4;
  const size_t xb = (size_t)b * 256 * NPIX;
  ushort* ob = xT + ((size_t)b * NPIX + p0) * 256 + cq * 64;
  for (int cc = 0; cc < 64; cc += 8) {
    us8 v[4];
    #pragma unroll
    for (int j = 0; j < 8; ++j) {
      const float4 q = *(const float4*)&x[xb + (size_t)(cq * 64 + cc + j) * NPIX + p0];
      v[0][j] = f2bf(q.x); v[1][j] = f2bf(q.y);
      v[2][j] = f2bf(q.z); v[3][j] = f2bf(q.w);
    }
    #pragma unroll
    for (int k = 0; k < 4; ++k)
      *(us8*)(ob + (size_t)k * 256 + cc) = v[k];
  }
}

// p12 (bf16 NCHW; c<128 = top-pooled, c>=128 = left-pooled)
//   -> sumT (bf16 [b][p][128]).  Thread = 4 px x 32 ch.
__global__ __launch_bounds__(256)
void sum_repack(const ushort* __restrict__ p12, ushort* __restrict__ sT)
{
  const int b  = blockIdx.z;
  const int cq = threadIdx.x >> 6;            // 32-channel chunk
  const int pg = threadIdx.x & 63;
  const int p0 = blockIdx.x * 256 + pg * 4;
  const size_t base = (size_t)b * 256 * NPIX;
  const ushort* P1 = p12 + base;
  const ushort* P2 = p12 + base + (size_t)128 * NPIX;
  ushort* ob = sT + ((size_t)b * NPIX + p0) * 128 + cq * 32;
  for (int cc = 0; cc < 32; cc += 8) {
    us8 v[4];
    #pragma unroll
    for (int j = 0; j < 8; ++j) {
      const size_t ci = (size_t)(cq * 32 + cc + j) * NPIX + p0;
      const ushort4 a = *(const ushort4*)&P1[ci];
      const ushort4 d = *(const ushort4*)&P2[ci];
      v[0][j] = f2bf(bf2f(a.x) + bf2f(d.x));
      v[1][j] = f2bf(bf2f(a.y) + bf2f(d.y));
      v[2][j] = f2bf(bf2f(a.z) + bf2f(d.z));
      v[3][j] = f2bf(bf2f(a.w) + bf2f(d.w));
    }
    #pragma unroll
    for (int k = 0; k < 4; ++k)
      *(us8*)(ob + (size_t)k * 128 + cc) = v[k];
  }
}

// reverse cummax along H, in place, bf16 [b][256][H][W] on channels co..co+127
__global__ __launch_bounds__(128)
void scan_h_rev(ushort* __restrict__ p, int co)
{
  const int bid = blockIdx.x;              // b*128 + c
  const int b = bid >> 7, c = bid & 127;
  ushort* base = p + ((size_t)(b * 256 + co + c)) * NPIX + threadIdx.x;
  float cur = bf2f(base[(HH - 1) * WW]);
  for (int hr = HH - 2; hr >= 0; --hr) {
    cur = fmaxf(cur, bf2f(base[hr * WW]));
    base[hr * WW] = f2bf(cur);
  }
}

// reverse cummax along W, in place; one wave per row, shfl suffix-scan.
__global__ __launch_bounds__(256)
void scan_w_rev(ushort* __restrict__ p, int co)
{
  const int lane = threadIdx.x & 63;
  const int rid  = blockIdx.x * 4 + (threadIdx.x >> 6);  // (b*128+c)*128 + h
  const int b = rid >> 14;
  const int rem = rid & 16383;
  const int c = rem >> 7, h = rem & 127;
  ushort* r = p + ((size_t)(b * 256 + co + c)) * NPIX + h * WW;
  const ushort2 u = ((const ushort2*)r)[lane];
  const float e0 = bf2f(u.x), e1 = bf2f(u.y);
  float m = fmaxf(e0, e1);
  #pragma unroll
  for (int off = 1; off < 64; off <<= 1) {
    const float o = __shfl_down(m, off, 64);
    if (lane + off < 64) m = fmaxf(m, o);
  }
  float s = __shfl_down(m, 1, 64);
  if (lane == 63) s = -3.4e38f;
  const float o1 = fmaxf(e1, s);
  const float o0 = fmaxf(e0, o1);
  ushort2 w; w.x = f2bf(o0); w.y = f2bf(o1);
  ((ushort2*)r)[lane] = w;
}

// ---------------------------------------------------------------------------
extern "C" void kernel_launch(void* const* d_in, const int* in_sizes, int n_in,
                              void* d_out, int out_size, void* d_ws, size_t ws_size,
                              hipStream_t stream) {
  const float* x    = (const float*)d_in[0];
  const float* w_p1 = (const float*)d_in[1];
  const float* g_p1 = (const float*)d_in[2];
  const float* b_p1 = (const float*)d_in[3];
  const float* m_p1 = (const float*)d_in[4];
  const float* v_p1 = (const float*)d_in[5];
  const float* w_p2 = (const float*)d_in[6];
  const float* g_p2 = (const float*)d_in[7];
  const float* b_p2 = (const float*)d_in[8];
  const float* m_p2 = (const float*)d_in[9];
  const float* v_p2 = (const float*)d_in[10];
  const float* w_pc = (const float*)d_in[11];
  const float* g_pb = (const float*)d_in[12];
  const float* b_pb = (const float*)d_in[13];
  const float* m_pb = (const float*)d_in[14];
  const float* v_pb = (const float*)d_in[15];
  const float* w_c1 = (const float*)d_in[16];
  const float* g_b1 = (const float*)d_in[17];
  const float* b_b1 = (const float*)d_in[18];
  const float* m_b1 = (const float*)d_in[19];
  const float* v_b1 = (const float*)d_in[20];
  const float* w_c2 = (const float*)d_in[21];
  const float* g_c2 = (const float*)d_in[22];
  const float* b_c2 = (const float*)d_in[23];
  const float* m_c2 = (const float*)d_in[24];
  const float* v_c2 = (const float*)d_in[25];

  char* ws = (char*)d_ws;
  // arena (bytes):
  ushort* xT      = (ushort*)(ws + 0);           // 32MB [b][p][256]
  ushort* p12     = (ushort*)(ws + 33554432);    // 32MB bf16 NCHW (top|left)
  ushort* relu1T  = (ushort*)(ws + 33554432);    // 32MB alias p12 (dead after sum)
  ushort* sumT    = (ushort*)(ws + 67108864);    // 16MB [b][p][128]
  ushort* wR_p12  = (ushort*)(ws + 100663296);   // 36 tiles  (1179648 B)
  ushort* wR_pcc1 = (ushort*)(ws + 101842944);   // 22 tiles  (720896 B)
  ushort* wR_c2   = (ushort*)(ws + 102563840);   // 36 tiles  (1179648 B)
  float*  tb_p12  = (float*)(ws + 103743488);    // 1KB each
  float*  tb_pc   = (float*)(ws + 103744512);
  float*  tb_c1   = (float*)(ws + 103745536);
  float*  tb_c2   = (float*)(ws + 103746560);
  ushort* zerop   = (ushort*)(ws + 103747584);   // 256B zeros

  hipMemsetAsync(zerop, 0, 256, stream);

  // fused weight repack (fold BN scale; emit tb)
  const int n_p  = 128 * 256 * 9;    // 294912 (p1 and p2 each)
  const int n_pc = 256 * 128 * 9;    // 294912
  const int n_c1 = 256 * 256 * 1;    // 65536
  const int n_c2 = 256 * 256 * 9;    // 589824
  WSeg s0 = {w_p1, g_p1, b_p1, m_p1, v_p1, wR_p12, tb_p12, 256, 256, 9, 0, 0,
             0, n_p};
  WSeg s1 = {w_p2, g_p2, b_p2, m_p2, v_p2, wR_p12, tb_p12, 256, 256, 9, 128, 0,
             n_p, 2 * n_p};
  WSeg s2 = {w_pc, g_pb, b_pb, m_pb, v_pb, wR_pcc1, tb_pc, 128, 256, 9, 0, 0,
             2 * n_p, 2 * n_p + n_pc};
  WSeg s3 = {w_c1, g_b1, b_b1, m_b1, v_b1, wR_pcc1, tb_c1, 256, 256, 1, 0, 18,
             2 * n_p + n_pc, 2 * n_p + n_pc + n_c1};
  WSeg s4 = {w_c2, g_c2, b_c2, m_c2, v_c2, wR_c2, tb_c2, 256, 256, 9, 0, 0,
             2 * n_p + n_pc + n_c1, 2 * n_p + n_pc + n_c1 + n_c2};
  const int n_all = 2 * n_p + n_pc + n_c1 + n_c2;
  wrepack_all<<<dim3((n_all + 255) / 256), 256, 0, stream>>>(s0, s1, s2, s3, s4);

  // x -> xT
  repack_x<<<dim3(NPIX / 256, 1, BB), 256, 0, stream>>>(x, xT);

  // p12 = relu(bn(conv3x3(x, [w_p1;w_p2])))  (bf16 NCHW, 256 planes)
  convgemm<256, 9, 0, 0, 0><<<dim3(HH * BB), 512, 0, stream>>>(
      xT, nullptr, wR_p12, tb_p12, nullptr, p12, zerop);

  // pools (in place): top on planes 0-127, left on planes 128-255
  scan_h_rev<<<dim3(BB * 128), 128, 0, stream>>>(p12, 0);
  scan_w_rev<<<dim3(BB * 128 * HH / 4), 256, 0, stream>>>(p12, 128);

  // sumT = top + left, transposed bf16
  sum_repack<<<dim3(NPIX / 256, 1, BB), 256, 0, stream>>>(p12, sumT);

  // relu1T = relu(bn(conv3x3(sumT)) + bn(conv1x1(x))), bf16 [b][p][256]
  // (fused pc + c1; writes transposed directly; overwrites p12 region)
  convgemm<128, 9, 256, 1, 4><<<dim3(HH * BB), 512, 0, stream>>>(
      sumT, xT, wR_pcc1, tb_pc, tb_c1, relu1T, zerop);

  // out = relu(bn(conv3x3(relu1T))), fp32 NCHW
  convgemm<256, 9, 0, 0, 3><<<dim3(HH * BB), 512, 0, stream>>>(
      relu1T, nullptr, wR_c2, tb_c2, nullptr, (void*)d_out, zerop);
}

// Round 7
// 300.151 us; speedup vs baseline: 1.0773x; 1.0773x over previous
//
#include <hip/hip_runtime.h>
#include <hip/hip_bf16.h>

#define HH 128
#define WW 128
#define BB 4
#define NPIX 16384            // HH*WW
#define EPSV 1e-5f

using bfrag = __attribute__((ext_vector_type(8))) short;     // 8 bf16 (4 VGPRs)
using f32x4 = __attribute__((ext_vector_type(4))) float;
using us8   = __attribute__((ext_vector_type(8))) unsigned short;

__device__ __forceinline__ float bf2f(ushort u) {
  union { unsigned int i; float f; } x; x.i = ((unsigned int)u) << 16; return x.f;
}
__device__ __forceinline__ ushort f2bf(float f) {
  union { float f; unsigned int i; } x; x.f = f;
  unsigned int r = x.i + 0x7fffu + ((x.i >> 16) & 1u);   // RNE
  return (ushort)(r >> 16);
}

#define GLOAD16(gsrc, ldst) \
  __builtin_amdgcn_global_load_lds( \
      (const __attribute__((address_space(1))) unsigned int*)(gsrc), \
      (__attribute__((address_space(3))) unsigned int*)(ldst), 16, 0, 0)

// ---------------------------------------------------------------------------
// Implicit-GEMM conv via MFMA.  Double-buffered LDS, ONE barrier per K-tile:
//   vmcnt(0) [tile t loads, issued a full compute ago] -> s_barrier ->
//   stage(t+1, other buf) -> compute(t).
// WAR-safe: the barrier proves all waves finished compute(t-1), which was the
// last reader of the buffer stage(t+1) writes.
// Tile: BM=128 outs x BN=128 px (one image row), 4 waves, wave = 64x64.
// 64KB LDS -> 2 blocks/CU (cross-block overlap covers barrier bubbles).
// A (weights) pre-repacked in global to the exact swizzled LDS image ->
// linear global_load_lds.  B (xT rows) staged with inverse-swizzled per-lane
// source (zero page feeds padding).  Optional second GEMM phase (CIN2/TAPS2)
// accumulates into the same tile (fuses the 1x1 skip conv).
// EPI: 0 = relu->bf16 NCHW, 3 = relu->fp32 NCHW,
//      4 = dual-bias, relu, LDS-transposed store -> bf16 [b][p][256].
// Grid: 1024 blocks 1D; XCD-locality swizzle: XCD g owns h in [16g,16g+16).
// ---------------------------------------------------------------------------
template<int CIN1, int TAPS1, int CIN2, int TAPS2, int EPI>
__global__ __launch_bounds__(256, 2)
void convgemm(const ushort* __restrict__ B1,    // [b][16384][CIN1] bf16
              const ushort* __restrict__ B2,    // [b][16384][CIN2] bf16 (opt)
              const ushort* __restrict__ wR,    // repacked weights (tiles)
              const float*  __restrict__ tb,    // bias per out-channel
              const float*  __restrict__ tb2,   // second bias (EPI 4)
              void*          __restrict__ outp,
              const ushort* __restrict__ zerop) // 256B of zeros
{
  __shared__ ushort lds[2][16384];              // per buf: 16KB A | 16KB B
  constexpr int nch1 = CIN1 / 64;
  constexpr int nch2 = (CIN2 > 0) ? CIN2 / 64 : 0;
  constexpr int NCH  = TAPS1 * nch1 + TAPS2 * nch2;

  // XCD-locality decode: g = XCD, owns 16 consecutive h for all (b, o-tile)
  const int g  = blockIdx.x & 7;
  const int r  = blockIdx.x >> 3;               // 0..127
  const int bo = r >> 4;                        // b*2 + o
  const int h  = g * 16 + (r & 15);
  const int o_base = (bo & 1) * 128;
  const int b  = bo >> 1;

  const int tid  = threadIdx.x;
  const int lane = tid & 63;
  const int wid  = tid >> 6;
  const int m0 = (wid >> 1) * 64;
  const int n0 = (wid & 1) * 64;

  f32x4 acc[4][4];
  #pragma unroll
  for (int i = 0; i < 4; ++i)
    #pragma unroll
    for (int j = 0; j < 4; ++j) acc[i][j] = (f32x4){0.f, 0.f, 0.f, 0.f};

  // staging lane constants (B side): per segment, LDS pixel-row & k-offset
  int rowB[4], ro1[4], ro2[4];
  #pragma unroll
  for (int s = 0; s < 4; ++s) {
    const int boff = (wid * 4 + s) * 1024 + lane * 16;   // byte off in B image
    rowB[s] = boff >> 7;                                  // pixel row 0..127
    const int sl8 = ((((boff >> 4) & 7) ^ (rowB[s] & 7)) << 3);
    ro1[s] = rowB[s] * CIN1 + sl8;
    ro2[s] = (CIN2 > 0) ? rowB[s] * CIN2 + sl8 : 0;
  }
  const size_t B1base = (size_t)b * NPIX * CIN1;
  const size_t B2base = (CIN2 > 0) ? (size_t)b * NPIX * CIN2 : 0;

  auto stage = [&](int t, int buf) {
    char* base = (char*)&lds[buf][0];
    const ushort* wsrc = wR + ((size_t)t * 256 + o_base) * 64;
    const ushort* bch;
    int zr; bool oob, ph2;
    if (CIN2 == 0 || t < TAPS1 * nch1) {
      const int tap = t / nch1, ch = t - tap * nch1;
      const int dy = (TAPS1 == 9) ? tap / 3 - 1 : 0;
      const int dx = (TAPS1 == 9) ? tap - (tap / 3) * 3 - 1 : 0;
      const int hy = h + dy;
      oob = (hy < 0) | (hy >= HH);
      zr  = (dx < 0) ? 0 : ((dx > 0) ? 127 : -1);
      bch = B1 + B1base + (size_t)(hy * WW + dx) * CIN1 + ch * 64;
      ph2 = false;
    } else {
      const int ch = t - TAPS1 * nch1;
      oob = false; zr = -1;
      bch = B2 + B2base + (size_t)(h * WW) * CIN2 + ch * 64;
      ph2 = true;
    }
    #pragma unroll
    for (int s = 0; s < 4; ++s) {
      const int off = (wid * 4 + s) * 1024;               // bytes
      GLOAD16((const char*)wsrc + off + lane * 16, base + off);
      const int roff = ph2 ? ro2[s] : ro1[s];
      const ushort* bs = (oob || rowB[s] == zr) ? zerop : (bch + roff);
      GLOAD16(bs, base + 16384 + off);
    }
  };

  auto compute = [&](int buf) {
    const char* base = (const char*)&lds[buf][0];
    bfrag af[2][4], bfv[2][4];                  // pre-read both kc frag sets
    #pragma unroll
    for (int kc = 0; kc < 2; ++kc) {
      const int sw = ((((kc << 2) | (lane >> 4)) ^ (lane & 7)) << 4); // bytes
      #pragma unroll
      for (int mf = 0; mf < 4; ++mf)
        af[kc][mf] = *(const bfrag*)(base + (m0 + mf * 16 + (lane & 15)) * 128 + sw);
      #pragma unroll
      for (int nf = 0; nf < 4; ++nf)
        bfv[kc][nf] = *(const bfrag*)(base + 16384 + (n0 + nf * 16 + (lane & 15)) * 128 + sw);
    }
    __builtin_amdgcn_s_setprio(1);
    #pragma unroll
    for (int kc = 0; kc < 2; ++kc)
      #pragma unroll
      for (int mf = 0; mf < 4; ++mf)
        #pragma unroll
        for (int nf = 0; nf < 4; ++nf)
          acc[mf][nf] = __builtin_amdgcn_mfma_f32_16x16x32_bf16(
              af[kc][mf], bfv[kc][nf], acc[mf][nf], 0, 0, 0);
    __builtin_amdgcn_s_setprio(0);
  };

  stage(0, 0);                                   // 8 loads in flight
  int cur = 0;
  for (int t = 0; t < NCH; ++t) {
    asm volatile("s_waitcnt vmcnt(0)" ::: "memory");  // tile t retired (issued
                                                      // a full compute ago)
    __builtin_amdgcn_s_barrier();                // t's LDS valid block-wide;
                                                 // all waves done reading cur^1
    __builtin_amdgcn_sched_barrier(0);           // no hoist above barrier
    if (t + 1 < NCH) stage(t + 1, cur ^ 1);      // overlap with compute(t)
    compute(cur);
    cur ^= 1;
  }

  if (EPI == 4) {
    // dual bias + relu, transpose via LDS, store bf16 [b][p][256] rows
    __syncthreads();                             // all compute done, LDS free
    ushort* ct = (ushort*)&lds[0][0];            // [128 px][136] (pad 8)
    const int pl0 = n0 + (lane & 15);
    #pragma unroll
    for (int mf = 0; mf < 4; ++mf) {
      #pragma unroll
      for (int r2 = 0; r2 < 4; ++r2) {
        const int ol = m0 + mf * 16 + (lane >> 4) * 4 + r2;
        const int o  = o_base + ol;
        const float bias = tb[o] + tb2[o];
        #pragma unroll
        for (int nf = 0; nf < 4; ++nf)
          ct[(pl0 + nf * 16) * 136 + ol] =
              f2bf(fmaxf(acc[mf][nf][r2] + bias, 0.f));
      }
    }
    __syncthreads();
    const int p  = tid >> 1;
    const int hf = tid & 1;
    ushort* dst = (ushort*)outp +
                  ((size_t)b * NPIX + h * WW + p) * 256 + o_base + hf * 64;
    const ushort* src = ct + p * 136 + hf * 64;
    #pragma unroll
    for (int j = 0; j < 8; ++j)
      *(us8*)(dst + j * 8) = *(const us8*)(src + j * 8);
    return;
  }

  // EPI 0 / 3: C row = o (coalesced over p within 16-lane groups)
  const int pc0 = h * WW + n0 + (lane & 15);
  #pragma unroll
  for (int mf = 0; mf < 4; ++mf) {
    #pragma unroll
    for (int r2 = 0; r2 < 4; ++r2) {
      const int o = o_base + m0 + mf * 16 + (lane >> 4) * 4 + r2;
      const float bias = tb[o];
      #pragma unroll
      for (int nf = 0; nf < 4; ++nf) {
        const int p = pc0 + nf * 16;
        float v = fmaxf(acc[mf][nf][r2] + bias, 0.f);
        const size_t oi = ((size_t)(b * 256 + o)) * NPIX + p;
        if (EPI == 0) ((ushort*)outp)[oi] = f2bf(v);
        else          ((float*)outp)[oi] = v;
      }
    }
  }
}

// ---------------------------------------------------------------------------
// fused weight repack: fold BN scale, bf16, swizzled LDS-image layout; emit tb.
// W is OIHW flat [COUT_local][CIN][TAPS]; tiles laid out cb + tap*nch + ch.
// ---------------------------------------------------------------------------
struct WSeg {
  const float *W, *g, *bb, *mm, *vv;
  ushort* dst; float* tb;
  int CIN, COUT, TAPS, o_off, cb, start, end;
};

__device__ __forceinline__ void wrepack_one(const WSeg& s, int e) {
  const int tap = e % s.TAPS;
  const int ci  = (e / s.TAPS) % s.CIN;
  const int o   = e / (s.TAPS * s.CIN);
  const int oi  = o + s.o_off;
  const float sc = s.g[o] * rsqrtf(s.vv[o] + EPSV);
  const int nch = s.CIN / 64;
  const int ch = ci >> 6, kl = ci & 63;
  const int slot = (kl >> 3) ^ (oi & 7);
  s.dst[(((size_t)((s.cb + tap * nch + ch) * s.COUT) + oi) << 6) +
        (slot << 3) + (kl & 7)] = f2bf(s.W[e] * sc);
  if (ci == 0 && tap == 0) s.tb[oi] = s.bb[o] - s.mm[o] * sc;
}

__global__ __launch_bounds__(256)
void wrepack_all(WSeg s0, WSeg s1, WSeg s2, WSeg s3, WSeg s4) {
  const int id = blockIdx.x * 256 + threadIdx.x;
  if (id < s0.end)      wrepack_one(s0, id - s0.start);
  else if (id < s1.end) wrepack_one(s1, id - s1.start);
  else if (id < s2.end) wrepack_one(s2, id - s2.start);
  else if (id < s3.end) wrepack_one(s3, id - s3.start);
  else if (id < s4.end) wrepack_one(s4, id - s4.start);
}

// ---------------------------------------------------------------------------
// x (fp32 NCHW) -> xT (bf16 [b][p][256]).  Thread = 4 px x 64 ch.
// ---------------------------------------------------------------------------
__global__ __launch_bounds__(256)
void repack_x(const float* __restrict__ x, ushort* __restrict__ xT)
{
  const int b  = blockIdx.z;
  const int cq = threadIdx.x >> 6;            // channel quarter
  const int pg = threadIdx.x & 63;
  const int p0 = blockIdx.x * 256 + pg * 4;
  const size_t xb = (size_t)b * 256 * NPIX;
  ushort* ob = xT + ((size_t)b * NPIX + p0) * 256 + cq * 64;
  for (int cc = 0; cc < 64; cc += 8) {
    us8 v[4];
    #pragma unroll
    for (int j = 0; j < 8; ++j) {
      const float4 q = *(const float4*)&x[xb + (size_t)(cq * 64 + cc + j) * NPIX + p0];
      v[0][j] = f2bf(q.x); v[1][j] = f2bf(q.y);
      v[2][j] = f2bf(q.z); v[3][j] = f2bf(q.w);
    }
    #pragma unroll
    for (int k = 0; k < 4; ++k)
      *(us8*)(ob + (size_t)k * 256 + cc) = v[k];
  }
}

// p12 (bf16 NCHW; c<128 = top-pooled, c>=128 = left-pooled)
//   -> sumT (bf16 [b][p][128]).  Thread = 4 px x 32 ch.
__global__ __launch_bounds__(256)
void sum_repack(const ushort* __restrict__ p12, ushort* __restrict__ sT)
{
  const int b  = blockIdx.z;
  const int cq = threadIdx.x >> 6;            // 32-channel chunk
  const int pg = threadIdx.x & 63;
  const int p0 = blockIdx.x * 256 + pg * 4;
  const size_t base = (size_t)b * 256 * NPIX;
  const ushort* P1 = p12 + base;
  const ushort* P2 = p12 + base + (size_t)128 * NPIX;
  ushort* ob = sT + ((size_t)b * NPIX + p0) * 128 + cq * 32;
  for (int cc = 0; cc < 32; cc += 8) {
    us8 v[4];
    #pragma unroll
    for (int j = 0; j < 8; ++j) {
      const size_t ci = (size_t)(cq * 32 + cc + j) * NPIX + p0;
      const ushort4 a = *(const ushort4*)&P1[ci];
      const ushort4 d = *(const ushort4*)&P2[ci];
      v[0][j] = f2bf(bf2f(a.x) + bf2f(d.x));
      v[1][j] = f2bf(bf2f(a.y) + bf2f(d.y));
      v[2][j] = f2bf(bf2f(a.z) + bf2f(d.z));
      v[3][j] = f2bf(bf2f(a.w) + bf2f(d.w));
    }
    #pragma unroll
    for (int k = 0; k < 4; ++k)
      *(us8*)(ob + (size_t)k * 128 + cc) = v[k];
  }
}

// merged pools, in place on p12 (bf16 [b][256][H][W]):
//  blocks 0..255:      reverse cummax along H on planes 0..127  (2 ch/block)
//  blocks 256..16639:  reverse cummax along W on planes 128..255 (4 rows/blk)
__global__ __launch_bounds__(256)
void scans(ushort* __restrict__ p)
{
  const int bid = blockIdx.x;
  if (bid < 256) {
    const int b = bid >> 6;
    const int c = (bid & 63) * 2 + (threadIdx.x >> 7);
    const int w = threadIdx.x & 127;
    ushort* base = p + ((size_t)(b * 256 + c)) * NPIX + w;
    float cur = bf2f(base[(HH - 1) * WW]);
    for (int hr = HH - 2; hr >= 0; --hr) {
      cur = fmaxf(cur, bf2f(base[hr * WW]));
      base[hr * WW] = f2bf(cur);
    }
  } else {
    const int lane = threadIdx.x & 63;
    const int rid  = (bid - 256) * 4 + (threadIdx.x >> 6); // b*128c*128h rows
    const int b = rid >> 14;
    const int rem = rid & 16383;
    const int c = rem >> 7, h = rem & 127;
    ushort* r = p + ((size_t)(b * 256 + 128 + c)) * NPIX + h * WW;
    const ushort2 u = ((const ushort2*)r)[lane];
    const float e0 = bf2f(u.x), e1 = bf2f(u.y);
    float m = fmaxf(e0, e1);
    #pragma unroll
    for (int off = 1; off < 64; off <<= 1) {
      const float o = __shfl_down(m, off, 64);
      if (lane + off < 64) m = fmaxf(m, o);
    }
    float s = __shfl_down(m, 1, 64);
    if (lane == 63) s = -3.4e38f;
    const float o1 = fmaxf(e1, s);
    const float o0 = fmaxf(e0, o1);
    ushort2 w2; w2.x = f2bf(o0); w2.y = f2bf(o1);
    ((ushort2*)r)[lane] = w2;
  }
}

// ---------------------------------------------------------------------------
extern "C" void kernel_launch(void* const* d_in, const int* in_sizes, int n_in,
                              void* d_out, int out_size, void* d_ws, size_t ws_size,
                              hipStream_t stream) {
  const float* x    = (const float*)d_in[0];
  const float* w_p1 = (const float*)d_in[1];
  const float* g_p1 = (const float*)d_in[2];
  const float* b_p1 = (const float*)d_in[3];
  const float* m_p1 = (const float*)d_in[4];
  const float* v_p1 = (const float*)d_in[5];
  const float* w_p2 = (const float*)d_in[6];
  const float* g_p2 = (const float*)d_in[7];
  const float* b_p2 = (const float*)d_in[8];
  const float* m_p2 = (const float*)d_in[9];
  const float* v_p2 = (const float*)d_in[10];
  const float* w_pc = (const float*)d_in[11];
  const float* g_pb = (const float*)d_in[12];
  const float* b_pb = (const float*)d_in[13];
  const float* m_pb = (const float*)d_in[14];
  const float* v_pb = (const float*)d_in[15];
  const float* w_c1 = (const float*)d_in[16];
  const float* g_b1 = (const float*)d_in[17];
  const float* b_b1 = (const float*)d_in[18];
  const float* m_b1 = (const float*)d_in[19];
  const float* v_b1 = (const float*)d_in[20];
  const float* w_c2 = (const float*)d_in[21];
  const float* g_c2 = (const float*)d_in[22];
  const float* b_c2 = (const float*)d_in[23];
  const float* m_c2 = (const float*)d_in[24];
  const float* v_c2 = (const float*)d_in[25];

  char* ws = (char*)d_ws;
  // arena (bytes):
  ushort* xT      = (ushort*)(ws + 0);           // 32MB [b][p][256]
  ushort* p12     = (ushort*)(ws + 33554432);    // 32MB bf16 NCHW (top|left)
  ushort* relu1T  = (ushort*)(ws + 33554432);    // 32MB alias p12 (dead after sum)
  ushort* sumT    = (ushort*)(ws + 67108864);    // 16MB [b][p][128]
  ushort* wR_p12  = (ushort*)(ws + 100663296);   // 36 tiles  (1179648 B)
  ushort* wR_pcc1 = (ushort*)(ws + 101842944);   // 22 tiles  (720896 B)
  ushort* wR_c2   = (ushort*)(ws + 102563840);   // 36 tiles  (1179648 B)
  float*  tb_p12  = (float*)(ws + 103743488);    // 1KB each
  float*  tb_pc   = (float*)(ws + 103744512);
  float*  tb_c1   = (float*)(ws + 103745536);
  float*  tb_c2   = (float*)(ws + 103746560);
  ushort* zerop   = (ushort*)(ws + 103747584);   // 256B zeros

  hipMemsetAsync(zerop, 0, 256, stream);

  // fused weight repack (fold BN scale; emit tb)
  const int n_p  = 128 * 256 * 9;    // 294912 (p1 and p2 each)
  const int n_pc = 256 * 128 * 9;    // 294912
  const int n_c1 = 256 * 256 * 1;    // 65536
  const int n_c2 = 256 * 256 * 9;    // 589824
  WSeg s0 = {w_p1, g_p1, b_p1, m_p1, v_p1, wR_p12, tb_p12, 256, 256, 9, 0, 0,
             0, n_p};
  WSeg s1 = {w_p2, g_p2, b_p2, m_p2, v_p2, wR_p12, tb_p12, 256, 256, 9, 128, 0,
             n_p, 2 * n_p};
  WSeg s2 = {w_pc, g_pb, b_pb, m_pb, v_pb, wR_pcc1, tb_pc, 128, 256, 9, 0, 0,
             2 * n_p, 2 * n_p + n_pc};
  WSeg s3 = {w_c1, g_b1, b_b1, m_b1, v_b1, wR_pcc1, tb_c1, 256, 256, 1, 0, 18,
             2 * n_p + n_pc, 2 * n_p + n_pc + n_c1};
  WSeg s4 = {w_c2, g_c2, b_c2, m_c2, v_c2, wR_c2, tb_c2, 256, 256, 9, 0, 0,
             2 * n_p + n_pc + n_c1, 2 * n_p + n_pc + n_c1 + n_c2};
  const int n_all = 2 * n_p + n_pc + n_c1 + n_c2;
  wrepack_all<<<dim3((n_all + 255) / 256), 256, 0, stream>>>(s0, s1, s2, s3, s4);

  // x -> xT
  repack_x<<<dim3(NPIX / 256, 1, BB), 256, 0, stream>>>(x, xT);

  // p12 = relu(bn(conv3x3(x, [w_p1;w_p2])))  (bf16 NCHW, 256 planes)
  convgemm<256, 9, 0, 0, 0><<<dim3(1024), 256, 0, stream>>>(
      xT, nullptr, wR_p12, tb_p12, nullptr, p12, zerop);

  // pools (in place): top on planes 0-127, left on planes 128-255
  scans<<<dim3(256 + 16384), 256, 0, stream>>>(p12);

  // sumT = top + left, transposed bf16
  sum_repack<<<dim3(NPIX / 256, 1, BB), 256, 0, stream>>>(p12, sumT);

  // relu1T = relu(bn(conv3x3(sumT)) + bn(conv1x1(x))), bf16 [b][p][256]
  // (fused pc + c1; writes transposed directly; overwrites p12 region)
  convgemm<128, 9, 256, 1, 4><<<dim3(1024), 256, 0, stream>>>(
      sumT, xT, wR_pcc1, tb_pc, tb_c1, relu1T, zerop);

  // out = relu(bn(conv3x3(relu1T))), fp32 NCHW
  convgemm<256, 9, 0, 0, 3><<<dim3(1024), 256, 0, stream>>>(
      relu1T, nullptr, wR_c2, tb_c2, nullptr, (void*)d_out, zerop);
}

// Round 8
// 287.078 us; speedup vs baseline: 1.1264x; 1.0455x over previous
//
#include <hip/hip_runtime.h>
#include <hip/hip_bf16.h>

#define HH 128
#define WW 128
#define BB 4
#define NPIX 16384            // HH*WW
#define EPSV 1e-5f

using bfrag = __attribute__((ext_vector_type(8))) short;     // 8 bf16 (4 VGPRs)
using f32x4 = __attribute__((ext_vector_type(4))) float;
using us8   = __attribute__((ext_vector_type(8))) unsigned short;

__device__ __forceinline__ float bf2f(ushort u) {
  union { unsigned int i; float f; } x; x.i = ((unsigned int)u) << 16; return x.f;
}
__device__ __forceinline__ ushort f2bf(float f) {
  union { float f; unsigned int i; } x; x.f = f;
  unsigned int r = x.i + 0x7fffu + ((x.i >> 16) & 1u);   // RNE
  return (ushort)(r >> 16);
}

#define GLOAD16(gsrc, ldst) \
  __builtin_amdgcn_global_load_lds( \
      (const __attribute__((address_space(1))) unsigned int*)(gsrc), \
      (__attribute__((address_space(3))) unsigned int*)(ldst), 16, 0, 0)

// ---------------------------------------------------------------------------
// Implicit-GEMM conv via MFMA — 256x256 tile, 8-wave, 2-phase-per-K-tile
// schedule with COUNTED vmcnt (never drains in the loop).
//   Tile: BM=256 outs x BN=256 px (two image rows 2h,2h+1) x BK=64.
//   8 waves as 2M x 4N; per-wave 128x64 (acc[8][4] f32x4 = 128 VGPR).
//   LDS: 2 buffers x (A 32KB | B 32KB) = 128 KB; 1 block/CU, grid = 256.
// Per K-tile t, loads issued in order B0..B3, A0,A2, A1,A3 (A segs by m-half):
//   phase0: vmcnt(2) [B+A0+A2 retired] -> barrier -> read B-all + A-half0,
//           issue stageB(t+1), 32 MFMA (acc rows 0-3)
//   phase1: vmcnt(4) [A1,A3 retired]  -> barrier -> read A-half1,
//           issue stageA(t+1), 32 MFMA (acc rows 4-7)
// WAR-safe: a wave passes a phase barrier only after lgkm-complete reads of
// the previous phase, so when any wave stages into buf^1 after the barrier,
// all waves' reads of buf^1 (tile t-1) have retired.
// EPI: 0 = relu->bf16 NCHW, 3 = relu->fp32 NCHW,
//      4 = dual-bias, relu, LDS-transposed store -> bf16 [b][p][256].
// ---------------------------------------------------------------------------
template<int CIN1, int TAPS1, int CIN2, int TAPS2, int EPI>
__global__ __launch_bounds__(512, 2)
void convgemm(const ushort* __restrict__ B1,    // [b][16384][CIN1] bf16
              const ushort* __restrict__ B2,    // [b][16384][CIN2] bf16 (opt)
              const ushort* __restrict__ wR,    // repacked weights (tiles)
              const float*  __restrict__ tb,    // bias per out-channel
              const float*  __restrict__ tb2,   // second bias (EPI 4)
              void*          __restrict__ outp,
              const ushort* __restrict__ zerop) // 256B of zeros
{
  __shared__ char ldsb[131072];                 // 2 x (A 32KB | B 32KB)
  constexpr int nch1 = CIN1 / 64;
  constexpr int nch2 = (CIN2 > 0) ? CIN2 / 64 : 0;
  constexpr int NCH  = TAPS1 * nch1 + TAPS2 * nch2;

  // grid 256: XCD g = bid&7 owns 32 contiguous nids (h-locality per L2)
  const int nid = (blockIdx.x & 7) * 32 + (blockIdx.x >> 3);
  const int b   = nid >> 6;
  const int h2  = (nid & 63) * 2;               // first of the two rows

  const int tid  = threadIdx.x;
  const int lane = tid & 63;
  const int wid  = tid >> 6;
  const int wc   = wid & 3;                     // N-wave (0..3)
  const int m0   = (wid >> 2) * 128;            // M-wave (0..1) -> 128 rows
  const int n0   = wc * 64;

  f32x4 acc[8][4];
  #pragma unroll
  for (int i = 0; i < 8; ++i)
    #pragma unroll
    for (int j = 0; j < 4; ++j) acc[i][j] = (f32x4){0.f, 0.f, 0.f, 0.f};

  // B staging constants: seg s covers pixel rows s*64..s*64+63 (8KB each)
  const int sl8 = (((tid & 7) ^ ((tid >> 3) & 7)) << 3);   // inv-swizzle k-off
  int ro1[4], ro2[4], w_[4], prow_[4];
  #pragma unroll
  for (int s = 0; s < 4; ++s) {
    const int rowB = s * 64 + (tid >> 3);       // pixel index 0..255
    prow_[s] = rowB >> 7;                       // 0: row 2h, 1: row 2h+1
    w_[s]    = rowB & 127;
    ro1[s]   = (prow_[s] * WW + w_[s]) * CIN1 + sl8;
    ro2[s]   = (CIN2 > 0) ? rowB * CIN2 + sl8 : 0;
  }
  const size_t B1base = (size_t)b * NPIX * CIN1;
  const size_t B2base = (CIN2 > 0) ? (size_t)b * NPIX * CIN2 : 0;

  auto stageB = [&](int t, int buf) {
    char* base = ldsb + buf * 65536 + 32768;
    if (CIN2 == 0 || t < TAPS1 * nch1) {
      const int tap = t / nch1, ch = t - tap * nch1;
      const int dy = (TAPS1 == 9) ? tap / 3 - 1 : 0;
      const int dx = (TAPS1 == 9) ? tap - (tap / 3) * 3 - 1 : 0;
      const int hy0 = h2 + dy;
      const bool oob0 = (hy0 < 0) | (hy0 > 127);
      const bool oob1 = (hy0 + 1 < 0) | (hy0 + 1 > 127);
      const int zr = (dx < 0) ? 0 : ((dx > 0) ? 127 : -1);
      const ushort* bch = B1 + B1base + (size_t)(hy0 * WW + dx) * CIN1 + ch * 64;
      #pragma unroll
      for (int s = 0; s < 4; ++s) {
        const bool bad = (prow_[s] ? oob1 : oob0) || (w_[s] == zr);
        const ushort* src = bad ? zerop : (bch + ro1[s]);
        GLOAD16(src, base + s * 8192 + tid * 16);
      }
    } else {
      const int ch = t - TAPS1 * nch1;
      const ushort* bch = B2 + B2base + (size_t)(h2 * WW) * CIN2 + ch * 64;
      #pragma unroll
      for (int s = 0; s < 4; ++s)
        GLOAD16(bch + ro2[s], base + s * 8192 + tid * 16);
    }
  };

  auto stageA = [&](int t, int buf) {           // order 0,2,1,3 (m-halves)
    char* base = ldsb + buf * 65536;
    const char* wsrc = (const char*)(wR + (size_t)t * (256 * 64));
    GLOAD16(wsrc + 0 * 8192 + tid * 16, base + 0 * 8192 + tid * 16);
    GLOAD16(wsrc + 2 * 8192 + tid * 16, base + 2 * 8192 + tid * 16);
    GLOAD16(wsrc + 1 * 8192 + tid * 16, base + 1 * 8192 + tid * 16);
    GLOAD16(wsrc + 3 * 8192 + tid * 16, base + 3 * 8192 + tid * 16);
  };

  stageB(0, 0);
  stageA(0, 0);                                  // 8 loads in flight
  int cur = 0;
  for (int t = 0; t < NCH; ++t) {
    const char* cbase = ldsb + cur * 65536;
    // ---- phase 0: B-all + A-half0 ----
    asm volatile("s_waitcnt vmcnt(2)" ::: "memory");
    __builtin_amdgcn_s_barrier();
    __builtin_amdgcn_sched_barrier(0);
    bfrag bf[2][4], af[2][4];
    #pragma unroll
    for (int kc = 0; kc < 2; ++kc) {
      const int sw = ((((kc << 2) | (lane >> 4)) ^ (lane & 7)) << 4);
      #pragma unroll
      for (int nf = 0; nf < 4; ++nf)
        bf[kc][nf] = *(const bfrag*)(cbase + 32768 +
                        (n0 + nf * 16 + (lane & 15)) * 128 + sw);
      #pragma unroll
      for (int mf = 0; mf < 4; ++mf)
        af[kc][mf] = *(const bfrag*)(cbase +
                        (m0 + mf * 16 + (lane & 15)) * 128 + sw);
    }
    if (t + 1 < NCH) stageB(t + 1, cur ^ 1);
    __builtin_amdgcn_s_setprio(1);
    #pragma unroll
    for (int kc = 0; kc < 2; ++kc)
      #pragma unroll
      for (int mf = 0; mf < 4; ++mf)
        #pragma unroll
        for (int nf = 0; nf < 4; ++nf)
          acc[mf][nf] = __builtin_amdgcn_mfma_f32_16x16x32_bf16(
              af[kc][mf], bf[kc][nf], acc[mf][nf], 0, 0, 0);
    __builtin_amdgcn_s_setprio(0);
    __builtin_amdgcn_sched_barrier(0);
    // ---- phase 1: A-half1 ----
    if (t + 1 < NCH) asm volatile("s_waitcnt vmcnt(4)" ::: "memory");
    else             asm volatile("s_waitcnt vmcnt(0)" ::: "memory");
    __builtin_amdgcn_s_barrier();
    __builtin_amdgcn_sched_barrier(0);
    bfrag ag[2][4];
    #pragma unroll
    for (int kc = 0; kc < 2; ++kc) {
      const int sw = ((((kc << 2) | (lane >> 4)) ^ (lane & 7)) << 4);
      #pragma unroll
      for (int mf = 0; mf < 4; ++mf)
        ag[kc][mf] = *(const bfrag*)(cbase +
                        (m0 + 64 + mf * 16 + (lane & 15)) * 128 + sw);
    }
    if (t + 1 < NCH) stageA(t + 1, cur ^ 1);
    __builtin_amdgcn_s_setprio(1);
    #pragma unroll
    for (int kc = 0; kc < 2; ++kc)
      #pragma unroll
      for (int mf = 0; mf < 4; ++mf)
        #pragma unroll
        for (int nf = 0; nf < 4; ++nf)
          acc[4 + mf][nf] = __builtin_amdgcn_mfma_f32_16x16x32_bf16(
              ag[kc][mf], bf[kc][nf], acc[4 + mf][nf], 0, 0, 0);
    __builtin_amdgcn_s_setprio(0);
    __builtin_amdgcn_sched_barrier(0);
    cur ^= 1;
  }

  if (EPI == 4) {
    // dual bias + relu; transpose via LDS in two 128-pixel passes
    ushort* ct = (ushort*)ldsb;                  // [128 px][264] per pass
    #pragma unroll
    for (int ph = 0; ph < 2; ++ph) {
      __syncthreads();
      if ((wc >> 1) == ph) {
        const int lp0 = (wc & 1) * 64 + (lane & 15);
        #pragma unroll
        for (int mf = 0; mf < 8; ++mf) {
          #pragma unroll
          for (int r2 = 0; r2 < 4; ++r2) {
            const int o = m0 + mf * 16 + (lane >> 4) * 4 + r2;
            const float bias = tb[o] + tb2[o];
            #pragma unroll
            for (int nf = 0; nf < 4; ++nf)
              ct[(lp0 + nf * 16) * 264 + o] =
                  f2bf(fmaxf(acc[mf][nf][r2] + bias, 0.f));
          }
        }
      }
      __syncthreads();
      const int lp = tid >> 2;
      const int q  = tid & 3;
      ushort* dst = (ushort*)outp +
          ((size_t)b * NPIX + (h2 + ph) * WW + lp) * 256 + q * 64;
      const ushort* src = ct + lp * 264 + q * 64;
      #pragma unroll
      for (int j = 0; j < 8; ++j)
        *(us8*)(dst + j * 8) = *(const us8*)(src + j * 8);
    }
    return;
  }

  // EPI 0 / 3: C[o][p]; p spans two rows (prow fixed per wave)
  const int prow = wc >> 1;
  const int hout = h2 + prow;
  const int wbase = (wc & 1) * 64 + (lane & 15);
  #pragma unroll
  for (int mf = 0; mf < 8; ++mf) {
    #pragma unroll
    for (int r2 = 0; r2 < 4; ++r2) {
      const int o = m0 + mf * 16 + (lane >> 4) * 4 + r2;
      const float bias = tb[o];
      #pragma unroll
      for (int nf = 0; nf < 4; ++nf) {
        const int w = wbase + nf * 16;
        float v = fmaxf(acc[mf][nf][r2] + bias, 0.f);
        const size_t oi = (((size_t)(b * 256 + o)) << 14) + hout * WW + w;
        if (EPI == 0) ((ushort*)outp)[oi] = f2bf(v);
        else          ((float*)outp)[oi] = v;
      }
    }
  }
}

// ---------------------------------------------------------------------------
// fused weight repack: fold BN scale, bf16, swizzled LDS-image layout; emit tb.
// W is OIHW flat [COUT_local][CIN][TAPS]; tiles laid out cb + tap*nch + ch.
// ---------------------------------------------------------------------------
struct WSeg {
  const float *W, *g, *bb, *mm, *vv;
  ushort* dst; float* tb;
  int CIN, COUT, TAPS, o_off, cb, start, end;
};

__device__ __forceinline__ void wrepack_one(const WSeg& s, int e) {
  const int tap = e % s.TAPS;
  const int ci  = (e / s.TAPS) % s.CIN;
  const int o   = e / (s.TAPS * s.CIN);
  const int oi  = o + s.o_off;
  const float sc = s.g[o] * rsqrtf(s.vv[o] + EPSV);
  const int nch = s.CIN / 64;
  const int ch = ci >> 6, kl = ci & 63;
  const int slot = (kl >> 3) ^ (oi & 7);
  s.dst[(((size_t)((s.cb + tap * nch + ch) * s.COUT) + oi) << 6) +
        (slot << 3) + (kl & 7)] = f2bf(s.W[e] * sc);
  if (ci == 0 && tap == 0) s.tb[oi] = s.bb[o] - s.mm[o] * sc;
}

__global__ __launch_bounds__(256)
void wrepack_all(WSeg s0, WSeg s1, WSeg s2, WSeg s3, WSeg s4) {
  const int id = blockIdx.x * 256 + threadIdx.x;
  if (id < s0.end)      wrepack_one(s0, id - s0.start);
  else if (id < s1.end) wrepack_one(s1, id - s1.start);
  else if (id < s2.end) wrepack_one(s2, id - s2.start);
  else if (id < s3.end) wrepack_one(s3, id - s3.start);
  else if (id < s4.end) wrepack_one(s4, id - s4.start);
}

// ---------------------------------------------------------------------------
// x (fp32 NCHW) -> xT (bf16 [b][p][256]).  Thread = 4 px x 64 ch.
// ---------------------------------------------------------------------------
__global__ __launch_bounds__(256)
void repack_x(const float* __restrict__ x, ushort* __restrict__ xT)
{
  const int b  = blockIdx.z;
  const int cq = threadIdx.x >> 6;            // channel quarter
  const int pg = threadIdx.x & 63;
  const int p0 = blockIdx.x * 256 + pg * 4;
  const size_t xb = (size_t)b * 256 * NPIX;
  ushort* ob = xT + ((size_t)b * NPIX + p0) * 256 + cq * 64;
  for (int cc = 0; cc < 64; cc += 8) {
    us8 v[4];
    #pragma unroll
    for (int j = 0; j < 8; ++j) {
      const float4 q = *(const float4*)&x[xb + (size_t)(cq * 64 + cc + j) * NPIX + p0];
      v[0][j] = f2bf(q.x); v[1][j] = f2bf(q.y);
      v[2][j] = f2bf(q.z); v[3][j] = f2bf(q.w);
    }
    #pragma unroll
    for (int k = 0; k < 4; ++k)
      *(us8*)(ob + (size_t)k * 256 + cc) = v[k];
  }
}

// p12 (bf16 NCHW; c<128 = top-pooled, c>=128 = left-pooled)
//   -> sumT (bf16 [b][p][128]).  Thread = 4 px x 32 ch.
__global__ __launch_bounds__(256)
void sum_repack(const ushort* __restrict__ p12, ushort* __restrict__ sT)
{
  const int b  = blockIdx.z;
  const int cq = threadIdx.x >> 6;            // 32-channel chunk
  const int pg = threadIdx.x & 63;
  const int p0 = blockIdx.x * 256 + pg * 4;
  const size_t base = (size_t)b * 256 * NPIX;
  const ushort* P1 = p12 + base;
  const ushort* P2 = p12 + base + (size_t)128 * NPIX;
  ushort* ob = sT + ((size_t)b * NPIX + p0) * 128 + cq * 32;
  for (int cc = 0; cc < 32; cc += 8) {
    us8 v[4];
    #pragma unroll
    for (int j = 0; j < 8; ++j) {
      const size_t ci = (size_t)(cq * 32 + cc + j) * NPIX + p0;
      const ushort4 a = *(const ushort4*)&P1[ci];
      const ushort4 d = *(const ushort4*)&P2[ci];
      v[0][j] = f2bf(bf2f(a.x) + bf2f(d.x));
      v[1][j] = f2bf(bf2f(a.y) + bf2f(d.y));
      v[2][j] = f2bf(bf2f(a.z) + bf2f(d.z));
      v[3][j] = f2bf(bf2f(a.w) + bf2f(d.w));
    }
    #pragma unroll
    for (int k = 0; k < 4; ++k)
      *(us8*)(ob + (size_t)k * 128 + cc) = v[k];
  }
}

// merged pools, in place on p12 (bf16 [b][256][H][W]):
//  blocks 0..255:      reverse cummax along H on planes 0..127  (2 ch/block)
//  blocks 256..16639:  reverse cummax along W on planes 128..255 (4 rows/blk)
__global__ __launch_bounds__(256)
void scans(ushort* __restrict__ p)
{
  const int bid = blockIdx.x;
  if (bid < 256) {
    const int b = bid >> 6;
    const int c = (bid & 63) * 2 + (threadIdx.x >> 7);
    const int w = threadIdx.x & 127;
    ushort* base = p + ((size_t)(b * 256 + c)) * NPIX + w;
    float cur = bf2f(base[(HH - 1) * WW]);
    for (int hr = HH - 2; hr >= 0; --hr) {
      cur = fmaxf(cur, bf2f(base[hr * WW]));
      base[hr * WW] = f2bf(cur);
    }
  } else {
    const int lane = threadIdx.x & 63;
    const int rid  = (bid - 256) * 4 + (threadIdx.x >> 6); // b*128c*128h rows
    const int b = rid >> 14;
    const int rem = rid & 16383;
    const int c = rem >> 7, h = rem & 127;
    ushort* r = p + ((size_t)(b * 256 + 128 + c)) * NPIX + h * WW;
    const ushort2 u = ((const ushort2*)r)[lane];
    const float e0 = bf2f(u.x), e1 = bf2f(u.y);
    float m = fmaxf(e0, e1);
    #pragma unroll
    for (int off = 1; off < 64; off <<= 1) {
      const float o = __shfl_down(m, off, 64);
      if (lane + off < 64) m = fmaxf(m, o);
    }
    float s = __shfl_down(m, 1, 64);
    if (lane == 63) s = -3.4e38f;
    const float o1 = fmaxf(e1, s);
    const float o0 = fmaxf(e0, o1);
    ushort2 w2; w2.x = f2bf(o0); w2.y = f2bf(o1);
    ((ushort2*)r)[lane] = w2;
  }
}

// ---------------------------------------------------------------------------
extern "C" void kernel_launch(void* const* d_in, const int* in_sizes, int n_in,
                              void* d_out, int out_size, void* d_ws, size_t ws_size,
                              hipStream_t stream) {
  const float* x    = (const float*)d_in[0];
  const float* w_p1 = (const float*)d_in[1];
  const float* g_p1 = (const float*)d_in[2];
  const float* b_p1 = (const float*)d_in[3];
  const float* m_p1 = (const float*)d_in[4];
  const float* v_p1 = (const float*)d_in[5];
  const float* w_p2 = (const float*)d_in[6];
  const float* g_p2 = (const float*)d_in[7];
  const float* b_p2 = (const float*)d_in[8];
  const float* m_p2 = (const float*)d_in[9];
  const float* v_p2 = (const float*)d_in[10];
  const float* w_pc = (const float*)d_in[11];
  const float* g_pb = (const float*)d_in[12];
  const float* b_pb = (const float*)d_in[13];
  const float* m_pb = (const float*)d_in[14];
  const float* v_pb = (const float*)d_in[15];
  const float* w_c1 = (const float*)d_in[16];
  const float* g_b1 = (const float*)d_in[17];
  const float* b_b1 = (const float*)d_in[18];
  const float* m_b1 = (const float*)d_in[19];
  const float* v_b1 = (const float*)d_in[20];
  const float* w_c2 = (const float*)d_in[21];
  const float* g_c2 = (const float*)d_in[22];
  const float* b_c2 = (const float*)d_in[23];
  const float* m_c2 = (const float*)d_in[24];
  const float* v_c2 = (const float*)d_in[25];

  char* ws = (char*)d_ws;
  // arena (bytes):
  ushort* xT      = (ushort*)(ws + 0);           // 32MB [b][p][256]
  ushort* p12     = (ushort*)(ws + 33554432);    // 32MB bf16 NCHW (top|left)
  ushort* relu1T  = (ushort*)(ws + 33554432);    // 32MB alias p12 (dead after sum)
  ushort* sumT    = (ushort*)(ws + 67108864);    // 16MB [b][p][128]
  ushort* wR_p12  = (ushort*)(ws + 100663296);   // 36 tiles  (1179648 B)
  ushort* wR_pcc1 = (ushort*)(ws + 101842944);   // 22 tiles  (720896 B)
  ushort* wR_c2   = (ushort*)(ws + 102563840);   // 36 tiles  (1179648 B)
  float*  tb_p12  = (float*)(ws + 103743488);    // 1KB each
  float*  tb_pc   = (float*)(ws + 103744512);
  float*  tb_c1   = (float*)(ws + 103745536);
  float*  tb_c2   = (float*)(ws + 103746560);
  ushort* zerop   = (ushort*)(ws + 103747584);   // 256B zeros

  hipMemsetAsync(zerop, 0, 256, stream);

  // fused weight repack (fold BN scale; emit tb)
  const int n_p  = 128 * 256 * 9;    // 294912 (p1 and p2 each)
  const int n_pc = 256 * 128 * 9;    // 294912
  const int n_c1 = 256 * 256 * 1;    // 65536
  const int n_c2 = 256 * 256 * 9;    // 589824
  WSeg s0 = {w_p1, g_p1, b_p1, m_p1, v_p1, wR_p12, tb_p12, 256, 256, 9, 0, 0,
             0, n_p};
  WSeg s1 = {w_p2, g_p2, b_p2, m_p2, v_p2, wR_p12, tb_p12, 256, 256, 9, 128, 0,
             n_p, 2 * n_p};
  WSeg s2 = {w_pc, g_pb, b_pb, m_pb, v_pb, wR_pcc1, tb_pc, 128, 256, 9, 0, 0,
             2 * n_p, 2 * n_p + n_pc};
  WSeg s3 = {w_c1, g_b1, b_b1, m_b1, v_b1, wR_pcc1, tb_c1, 256, 256, 1, 0, 18,
             2 * n_p + n_pc, 2 * n_p + n_pc + n_c1};
  WSeg s4 = {w_c2, g_c2, b_c2, m_c2, v_c2, wR_c2, tb_c2, 256, 256, 9, 0, 0,
             2 * n_p + n_pc + n_c1, 2 * n_p + n_pc + n_c1 + n_c2};
  const int n_all = 2 * n_p + n_pc + n_c1 + n_c2;
  wrepack_all<<<dim3((n_all + 255) / 256), 256, 0, stream>>>(s0, s1, s2, s3, s4);

  // x -> xT
  repack_x<<<dim3(NPIX / 256, 1, BB), 256, 0, stream>>>(x, xT);

  // p12 = relu(bn(conv3x3(x, [w_p1;w_p2])))  (bf16 NCHW, 256 planes)
  convgemm<256, 9, 0, 0, 0><<<dim3(256), 512, 0, stream>>>(
      xT, nullptr, wR_p12, tb_p12, nullptr, p12, zerop);

  // pools (in place): top on planes 0-127, left on planes 128-255
  scans<<<dim3(256 + 16384), 256, 0, stream>>>(p12);

  // sumT = top + left, transposed bf16
  sum_repack<<<dim3(NPIX / 256, 1, BB), 256, 0, stream>>>(p12, sumT);

  // relu1T = relu(bn(conv3x3(sumT)) + bn(conv1x1(x))), bf16 [b][p][256]
  // (fused pc + c1; writes transposed directly; overwrites p12 region)
  convgemm<128, 9, 256, 1, 4><<<dim3(256), 512, 0, stream>>>(
      sumT, xT, wR_pcc1, tb_pc, tb_c1, relu1T, zerop);

  // out = relu(bn(conv3x3(relu1T))), fp32 NCHW
  convgemm<256, 9, 0, 0, 3><<<dim3(256), 512, 0, stream>>>(
      relu1T, nullptr, wR_c2, tb_c2, nullptr, (void*)d_out, zerop);
}